// Round 7
// baseline (57.682 us; speedup 1.0000x reference)
//
#include <hip/hip_runtime.h>
#include <stdint.h>

#define CIN   128
#define COUT  256
#define HW    56
#define SP    3136      // 56*56
#define NIMG  32
#define KTOT  (CIN*9)   // 1152

typedef unsigned char u8;
using i32x4 = __attribute__((ext_vector_type(4))) int;

__device__ __forceinline__ u8 sgn_i8(float v) {
  return v > 0.f ? (u8)1 : (v < 0.f ? (u8)0xFF : (u8)0);
}

__device__ __forceinline__ void gl_lds16(const void* g, void* l) {
  __builtin_amdgcn_global_load_lds(
      (const __attribute__((address_space(1))) void*)g,
      (__attribute__((address_space(3))) void*)l, 16, 0, 0);
}

// ---- prepass: binarize + K-transpose weights to i8: wT[o][q*128+c] ----
__global__ void prep_w(const float* __restrict__ w, u8* __restrict__ wT) {
  int idx = blockIdx.x * 256 + threadIdx.x;
  if (idx >= COUT * KTOT) return;
  int o = idx / KTOT;
  int r = idx - o * KTOT;
  int q = r >> 7;
  int c = r & 127;
  wT[idx] = sgn_i8(w[(size_t)(o * CIN + c) * 9 + q]);
}

// ---- main: implicit-GEMM binarized conv, fused x-binarize halo ----
// tile: 128 Cout x 224 pixels (4 h-rows, image-aligned: 224*14 = 3136).
// Halo staged once per block DIRECTLY FROM x (f32 NCHW): thread t<348 owns
// slot t = (vh,col), reads 128 channels (coalesced across lanes), binarizes,
// packs, ds_write_b128 to swizzled dest. A (wT i8) staged per tap via
// global_load_lds, double-buffered, pre-swizzled source.
// 512 thr = 8 waves (4M x 2N), per-wave 32x112, acc[2][7].
// LDS = 48KB halo + 2x16KB A = 80KB -> 2 blocks/CU (16 waves/CU).
__global__ __launch_bounds__(512, 4) void conv_mfma(
    const u8* __restrict__ wT, const float* __restrict__ x,
    const float* __restrict__ bias, float* __restrict__ out) {
  __shared__ u8 halo[49152];    // 384 slots x 128 B (348 real)
  __shared__ u8 As[2][16384];   // [128 Cout][128 cin] per tap, swizzled chunks

  // XCD-chunked swizzle (896 = 8*112, bijective); mt pairs stay adjacent.
  const int bid0 = blockIdx.x;
  const int bid  = (bid0 & 7) * 112 + (bid0 >> 3);
  const int mt  = bid & 1;        // Cout half
  const int nt2 = bid >> 1;       // 0..447
  const int n    = nt2 / 14;      // image
  const int hblk = nt2 - n * 14;  // 4-row block
  const int h0   = hblk * 4;
  const int sp0  = hblk * 224;

  const int t  = threadIdx.x;
  const int wv = t >> 6;          // 0..7
  const int ln = t & 63;

  // ---- A staging geometry (pre-swizzled source chunk) ----
  const int tRow = t >> 3;                  // 0..63
  const int chs  = (t & 7) ^ (tRow & 7);
  const u8* wTbase = wT + (size_t)(mt * 128 + tRow) * KTOT + (chs << 4);
  auto stageA = [&](int b, int q) {
#pragma unroll
    for (int c = 0; c < 2; ++c)
      gl_lds16(wTbase + (size_t)c * 64 * KTOT + q * CIN,
               &As[b][c * 8192 + wv * 1024]);
  };
  stageA(0, 0);   // issue first A tap before halo work

  // ---- fused halo staging: thread t<348 owns one slot ----
  if (t < 348) {
    const int vh  = t / 58;           // 0..5
    const int col = t - vh * 58;      // 0..57
    const int gh  = h0 - 1 + vh;
    const bool valid = ((unsigned)gh < HW) && (col >= 1) && (col <= 56);
    const float* xp = x + (size_t)n * CIN * SP + gh * HW + (col - 1);
    const int sw = t & 7;
#pragma unroll
    for (int k = 0; k < 8; ++k) {     // 8 chunks of 16 channels
      uint32_t d[4];
#pragma unroll
      for (int dd = 0; dd < 4; ++dd) {
        uint32_t pk = 0;
#pragma unroll
        for (int b = 0; b < 4; ++b) {
          const int c = k * 16 + dd * 4 + b;
          float v = valid ? xp[(size_t)c * SP] : 0.f;
          uint32_t s8 = v > 0.f ? 0x01u : (v < 0.f ? 0xFFu : 0x00u);
          pk |= s8 << (8 * b);
        }
        d[dd] = pk;
      }
      uint4 u4; u4.x = d[0]; u4.y = d[1]; u4.z = d[2]; u4.w = d[3];
      *(uint4*)&halo[(t << 7) + ((k ^ sw) << 4)] = u4;
    }
  }

  // ---- fragment geometry (4M x 2N wave grid, per-wave 32x112) ----
  const int wm = wv >> 1, wn = wv & 1;
  const int lr = ln & 15, kg = ln >> 4;
  const int kgs0 = kg << 4;
  const int rdA0 = ((wm * 32 + lr) << 7) + ((kg ^ (lr & 7)) << 4);
  const int rdA1 = rdA0 + (16 << 7);

  int slotj[7];
#pragma unroll
  for (int j = 0; j < 7; ++j) {
    const int px = wn * 112 + j * 16 + lr;  // 0..223
    const int ph = px / 56;
    slotj[j] = (1 + ph) * 58 + (px - ph * 56) + 1;
  }

  i32x4 acc[2][7];
#pragma unroll
  for (int i = 0; i < 2; ++i)
#pragma unroll
    for (int j = 0; j < 7; ++j) acc[i][j] = (i32x4){0, 0, 0, 0};

  constexpr int DC[9] = {-59, -58, -57, -1, 0, 1, 57, 58, 59};

#pragma unroll
  for (int q = 0; q < 9; ++q) {
    __syncthreads();                 // halo (ds_write) + As[q&1] (vmcnt) ready
    if (q < 8) stageA((q + 1) & 1, q + 1);
    const int buf = q & 1;
    int ba[7];
#pragma unroll
    for (int j = 0; j < 7; ++j) {
      const int s_t = slotj[j] + DC[q];
      ba[j] = (s_t << 7) + (kgs0 ^ ((s_t & 7) << 4));
    }
#pragma unroll
    for (int kc = 0; kc < 2; ++kc) {
      const i32x4 af0 = *(const i32x4*)&As[buf][rdA0 ^ (kc << 6)];
      const i32x4 af1 = *(const i32x4*)&As[buf][rdA1 ^ (kc << 6)];
#pragma unroll
      for (int j = 0; j < 7; ++j) {
        const i32x4 bf = *(const i32x4*)&halo[ba[j] ^ (kc << 6)];
        acc[0][j] = __builtin_amdgcn_mfma_i32_16x16x64_i8(af0, bf, acc[0][j], 0, 0, 0);
        acc[1][j] = __builtin_amdgcn_mfma_i32_16x16x64_i8(af1, bf, acc[1][j], 0, 0, 0);
      }
    }
  }

  // ---- epilogue: C[m][px] -> out[n][m][sp0+px], + sign(bias[m]) ----
  const int mrow = mt * 128 + wm * 32 + kg * 4;
  float* obase = out + (size_t)n * COUT * SP + sp0 + wn * 112 + lr;
#pragma unroll
  for (int i = 0; i < 2; ++i) {
#pragma unroll
    for (int r = 0; r < 4; ++r) {
      const int m = mrow + i * 16 + r;
      const float bv = bias[m];
      const float sb = bv > 0.f ? 1.f : (bv < 0.f ? -1.f : 0.f);
      float* op = obase + (size_t)m * SP;
#pragma unroll
      for (int j = 0; j < 7; ++j)
        op[j * 16] = (float)acc[i][j][r] + sb;
    }
  }
}

// ---- fallback if workspace is too small: direct conv (slow but correct) ----
__global__ void conv_naive(const float* __restrict__ x, const float* __restrict__ w,
                           const float* __restrict__ bias, float* __restrict__ out) {
  int idx = blockIdx.x * 256 + threadIdx.x;
  const int total = NIMG * COUT * SP;
  if (idx >= total) return;
  int sp = idx % SP;
  int o  = (idx / SP) % COUT;
  int nn = idx / (SP * COUT);
  int h = sp / HW, wx = sp - (sp / HW) * HW;
  float acc = 0.f;
  for (int c = 0; c < CIN; ++c) {
    const float* xp = x + (size_t)(nn * CIN + c) * SP;
    const float* wp = w + (size_t)(o * CIN + c) * 9;
    for (int kh = 0; kh < 3; ++kh) {
      int hhh = h + kh - 1;
      if ((unsigned)hhh >= HW) continue;
      for (int kw = 0; kw < 3; ++kw) {
        int www = wx + kw - 1;
        if ((unsigned)www >= HW) continue;
        float xv = xp[hhh * HW + www];
        float wv = wp[kh * 3 + kw];
        float xs = xv > 0.f ? 1.f : (xv < 0.f ? -1.f : 0.f);
        float wsn = wv > 0.f ? 1.f : (wv < 0.f ? -1.f : 0.f);
        acc += xs * wsn;
      }
    }
  }
  float bv = bias[o];
  out[idx] = acc + (bv > 0.f ? 1.f : (bv < 0.f ? -1.f : 0.f));
}

extern "C" void kernel_launch(void* const* d_in, const int* in_sizes, int n_in,
                              void* d_out, int out_size, void* d_ws, size_t ws_size,
                              hipStream_t stream) {
  const float* x    = (const float*)d_in[0];
  const float* w    = (const float*)d_in[1];
  const float* bias = (const float*)d_in[2];
  float* out = (float*)d_out;

  const size_t need = (size_t)COUT * KTOT + 512;   // ~295 KB
  if (ws_size >= need) {
    u8* wT8 = (u8*)d_ws;                           // 256x1152 i8
    prep_w<<<(COUT * KTOT + 255) / 256, 256, 0, stream>>>(w, wT8);
    conv_mfma<<<896, 512, 0, stream>>>(wT8, x, bias, out);
  } else {
    const int total = NIMG * COUT * SP;
    conv_naive<<<(total + 255) / 256, 256, 0, stream>>>(x, w, bias, out);
  }
}